// Round 1
// baseline (1782.110 us; speedup 1.0000x reference)
//
#include <hip/hip_runtime.h>
#include <hip/hip_bf16.h>

#define BM 64
#define BN 64
#define BK 16

// ---------------- row L2-normalize: out[r,:] = in[r,:] / ||in[r,:]|| ----------------
__global__ __launch_bounds__(256) void normalize_rows(const float* __restrict__ in,
                                                      float* __restrict__ out, int D) {
    int row = blockIdx.x;
    const float* x = in + (size_t)row * D;
    float* o = out + (size_t)row * D;
    float s = 0.0f;
    for (int i = threadIdx.x; i < D; i += 256) { float t = x[i]; s += t * t; }
    __shared__ float sm[4];
    #pragma unroll
    for (int off = 32; off; off >>= 1) s += __shfl_down(s, off, 64);
    if ((threadIdx.x & 63) == 0) sm[threadIdx.x >> 6] = s;
    __syncthreads();
    float tot = sm[0] + sm[1] + sm[2] + sm[3];
    float inv = 1.0f / sqrtf(tot);
    for (int i = threadIdx.x; i < D; i += 256) o[i] = x[i] * inv;
}

// ---------------- C[M,N] = A[M,K] @ B[K,N]  (no guards: M%64==0, N%64==0, K%16==0) ----
__global__ __launch_bounds__(256) void gemm_nn(const float* __restrict__ A,
                                               const float* __restrict__ B,
                                               float* __restrict__ Co,
                                               int M, int N, int K) {
    __shared__ alignas(16) float As[BK][BM + 4];
    __shared__ alignas(16) float Bs[BK][BN];
    int id = threadIdx.x;
    int tx = id & 15, ty = id >> 4;
    int row0 = blockIdx.y * BM, col0 = blockIdx.x * BN;
    float acc[4][4] = {};
    for (int k0 = 0; k0 < K; k0 += BK) {
        #pragma unroll
        for (int i = 0; i < 4; i++) {
            int idx = id + i * 256;
            int r = idx >> 4, cc = idx & 15;           // A tile 64x16
            As[cc][r] = A[(size_t)(row0 + r) * K + k0 + cc];
        }
        #pragma unroll
        for (int i = 0; i < 4; i++) {
            int idx = id + i * 256;
            int r = idx >> 6, cc = idx & 63;           // B tile 16x64
            Bs[r][cc] = B[(size_t)(k0 + r) * N + col0 + cc];
        }
        __syncthreads();
        #pragma unroll
        for (int kk = 0; kk < BK; kk++) {
            float4 a4 = *(const float4*)&As[kk][ty * 4];
            float4 b4 = *(const float4*)&Bs[kk][tx * 4];
            float av[4] = {a4.x, a4.y, a4.z, a4.w};
            float bv[4] = {b4.x, b4.y, b4.z, b4.w};
            #pragma unroll
            for (int i = 0; i < 4; i++)
                #pragma unroll
                for (int j = 0; j < 4; j++) acc[i][j] += av[i] * bv[j];
        }
        __syncthreads();
    }
    #pragma unroll
    for (int i = 0; i < 4; i++) {
        size_t r = (size_t)(row0 + ty * 4 + i) * N + col0 + tx * 4;
        float4 o = make_float4(acc[i][0], acc[i][1], acc[i][2], acc[i][3]);
        *(float4*)&Co[r] = o;
    }
}

// ------------- C[M,N] = scale*(A[M,K] @ B[N,K]^T) + bias[n]  (N guarded) -------------
__global__ __launch_bounds__(256) void gemm_nt(const float* __restrict__ A,
                                               const float* __restrict__ B,
                                               const float* __restrict__ bias,
                                               float* __restrict__ Co,
                                               int M, int N, int K, float scale) {
    __shared__ alignas(16) float As[BK][BM + 4];
    __shared__ alignas(16) float Bs[BK][BN + 4];
    int id = threadIdx.x;
    int tx = id & 15, ty = id >> 4;
    int row0 = blockIdx.y * BM, col0 = blockIdx.x * BN;
    float acc[4][4] = {};
    for (int k0 = 0; k0 < K; k0 += BK) {
        #pragma unroll
        for (int i = 0; i < 4; i++) {
            int idx = id + i * 256;
            int r = idx >> 4, cc = idx & 15;
            As[cc][r] = A[(size_t)(row0 + r) * K + k0 + cc];
            int n = col0 + r;
            Bs[cc][r] = (n < N) ? B[(size_t)n * K + k0 + cc] : 0.0f;
        }
        __syncthreads();
        #pragma unroll
        for (int kk = 0; kk < BK; kk++) {
            float4 a4 = *(const float4*)&As[kk][ty * 4];
            float4 b4 = *(const float4*)&Bs[kk][tx * 4];
            float av[4] = {a4.x, a4.y, a4.z, a4.w};
            float bv[4] = {b4.x, b4.y, b4.z, b4.w};
            #pragma unroll
            for (int i = 0; i < 4; i++)
                #pragma unroll
                for (int j = 0; j < 4; j++) acc[i][j] += av[i] * bv[j];
        }
        __syncthreads();
    }
    #pragma unroll
    for (int i = 0; i < 4; i++) {
        int row = row0 + ty * 4 + i;
        #pragma unroll
        for (int j = 0; j < 4; j++) {
            int col = col0 + tx * 4 + j;
            if (col < N) {
                float v = acc[i][j] * scale;
                if (bias) v += bias[col];
                Co[(size_t)row * N + col] = v;
            }
        }
    }
}

// --------- sparsemax over rows of length 512, in-place capable (1 wave/row) ----------
__global__ __launch_bounds__(64) void sparsemax_k(const float* __restrict__ S,
                                                  float* __restrict__ attn) {
    int row = blockIdx.x;
    int lane = threadIdx.x;
    const float* z = S + (size_t)row * 512;
    float v[8];
    #pragma unroll
    for (int j = 0; j < 8; j++) v[j] = z[lane + 64 * j];
    float mx = v[0];
    #pragma unroll
    for (int j = 1; j < 8; j++) mx = fmaxf(mx, v[j]);
    #pragma unroll
    for (int off = 1; off < 64; off <<= 1) mx = fmaxf(mx, __shfl_xor(mx, off, 64));
    // bisect tau in [mx-1, mx] for sum(relu(z - tau)) == 1
    float lo = mx - 1.0f, hi = mx;
    for (int it = 0; it < 30; it++) {
        float tau = 0.5f * (lo + hi);
        float s = 0.0f;
        #pragma unroll
        for (int j = 0; j < 8; j++) s += fmaxf(v[j] - tau, 0.0f);
        #pragma unroll
        for (int off = 1; off < 64; off <<= 1) s += __shfl_xor(s, off, 64);
        if (s >= 1.0f) lo = tau; else hi = tau;   // bit-identical across lanes
    }
    float tau = 0.5f * (lo + hi);
    float* o = attn + (size_t)row * 512;
    #pragma unroll
    for (int j = 0; j < 8; j++) o[lane + 64 * j] = fmaxf(v[j] - tau, 0.0f);
}

extern "C" void kernel_launch(void* const* d_in, const int* in_sizes, int n_in,
                              void* d_out, int out_size, void* d_ws, size_t ws_size,
                              hipStream_t stream) {
    const float* x        = (const float*)d_in[0];   // [16384,1024]
    const float* concepts = (const float*)d_in[1];   // [512,1024]
    const float* Wq       = (const float*)d_in[2];   // [1024,1024]
    const float* Wk       = (const float*)d_in[3];   // [1024,1024]
    const float* fc_w     = (const float*)d_in[4];   // [1000,1024]
    const float* fc_b     = (const float*)d_in[5];   // [1000]

    const int B = 16384, D = 1024, C = 512, N = 1000;

    float* out  = (float*)d_out;                       // [B,N]
    float* attn = out + (size_t)B * N;                 // [B,C]
    float* sim  = attn + (size_t)B * C;                // [C,C]

    float* ws   = (float*)d_ws;
    float* c    = ws;                                  // [C,D]  2 MB
    float* kmat = c + (size_t)C * D;                   // [C,D]  2 MB
    float* q    = kmat + (size_t)C * D;                // [B,D] 64 MB (reused as summary)

    // 1. c = normalize(concepts)
    normalize_rows<<<C, 256, 0, stream>>>(concepts, c, D);
    // 2. k = c @ Wk ; sim = c @ c^T
    gemm_nn<<<dim3(D / 64, C / 64), 256, 0, stream>>>(c, Wk, kmat, C, D, D);
    gemm_nt<<<dim3(C / 64, C / 64), 256, 0, stream>>>(c, c, nullptr, sim, C, C, D, 1.0f);
    // 3. q = x @ Wq
    gemm_nn<<<dim3(D / 64, B / 64), 256, 0, stream>>>(x, Wq, q, B, D, D);
    // 4. scores = (q @ k^T) / sqrt(D)  -> written into the attn slot of d_out
    gemm_nt<<<dim3(C / 64, B / 64), 256, 0, stream>>>(q, kmat, nullptr, attn, B, C, D, 0.03125f);
    // 5. attn = sparsemax(scores), in place (one wave per row, register-resident)
    sparsemax_k<<<B, 64, 0, stream>>>(attn, attn);
    // 6. summary = attn @ c   (overwrites q buffer), then row-normalize
    float* summary = q;
    gemm_nn<<<dim3(D / 64, B / 64), 256, 0, stream>>>(attn, c, summary, B, D, C);
    normalize_rows<<<B, 256, 0, stream>>>(summary, summary, D);
    // 7. out = summary @ fc_w^T + fc_b
    gemm_nt<<<dim3((N + 63) / 64, B / 64), 256, 0, stream>>>(summary, fc_w, fc_b, out, B, N, D, 1.0f);
}

// Round 2
// 468.185 us; speedup vs baseline: 3.8064x; 3.8064x over previous
//
#include <hip/hip_runtime.h>
#include <hip/hip_bf16.h>
#include <stdint.h>

typedef __attribute__((ext_vector_type(8))) short short8;
typedef __attribute__((ext_vector_type(4))) float floatx4;

__device__ __forceinline__ ushort f2b(float f) {
    union { float f; uint32_t u; } v; v.f = f;
    uint32_t r = (v.u + 0x7fffu + ((v.u >> 16) & 1u)) >> 16;
    return (ushort)r;
}
__device__ __forceinline__ float b2f(ushort b) {
    union { uint32_t u; float f; } v; v.u = ((uint32_t)b) << 16;
    return v.f;
}

__device__ __forceinline__ void gl_lds16(const void* g, void* l) {
    __builtin_amdgcn_global_load_lds(
        (const __attribute__((address_space(1))) void*)g,
        (__attribute__((address_space(3))) void*)l, 16, 0, 0);
}

// ---------------- elementwise f32 -> bf16 (float4 in, ushort4 out) ----------------
__global__ __launch_bounds__(256) void convert_f32_bf16(const float* __restrict__ in,
                                                        ushort* __restrict__ out, int n4) {
    int i = blockIdx.x * 256 + threadIdx.x;
    if (i < n4) {
        float4 v = ((const float4*)in)[i];
        ushort4 o;
        o.x = f2b(v.x); o.y = f2b(v.y); o.z = f2b(v.z); o.w = f2b(v.w);
        ((ushort4*)out)[i] = o;
    }
}

// ---------------- transpose f32[R,C] -> bf16[C,R] ----------------
__global__ __launch_bounds__(256) void transpose_f32_to_bf16(const float* __restrict__ in,
                                                             ushort* __restrict__ out,
                                                             int R, int Cc) {
    __shared__ ushort t[32][33];
    int bx = blockIdx.x * 32;   // input col
    int by = blockIdx.y * 32;   // input row
    int tx = threadIdx.x & 31, ty = threadIdx.x >> 5;  // ty in 0..7
    #pragma unroll
    for (int i = 0; i < 32; i += 8)
        t[ty + i][tx] = f2b(in[(size_t)(by + ty + i) * Cc + bx + tx]);
    __syncthreads();
    #pragma unroll
    for (int i = 0; i < 32; i += 8)
        out[(size_t)(bx + ty + i) * R + by + tx] = t[tx][ty + i];
}

// ---------------- transpose bf16[R,C] -> bf16[C,R] ----------------
__global__ __launch_bounds__(256) void transpose_bf16(const ushort* __restrict__ in,
                                                      ushort* __restrict__ out,
                                                      int R, int Cc) {
    __shared__ ushort t[32][33];
    int bx = blockIdx.x * 32;
    int by = blockIdx.y * 32;
    int tx = threadIdx.x & 31, ty = threadIdx.x >> 5;
    #pragma unroll
    for (int i = 0; i < 32; i += 8)
        t[ty + i][tx] = in[(size_t)(by + ty + i) * Cc + bx + tx];
    __syncthreads();
    #pragma unroll
    for (int i = 0; i < 32; i += 8)
        out[(size_t)(bx + ty + i) * R + by + tx] = t[tx][ty + i];
}

// ---------------- row L2-normalize f32 in -> bf16 out ----------------
__global__ __launch_bounds__(256) void normalize_f32_to_bf16(const float* __restrict__ in,
                                                             ushort* __restrict__ out, int D) {
    int row = blockIdx.x;
    const float* x = in + (size_t)row * D;
    float s = 0.0f;
    for (int i = threadIdx.x; i < D; i += 256) { float t = x[i]; s += t * t; }
    __shared__ float sm[4];
    #pragma unroll
    for (int off = 32; off; off >>= 1) s += __shfl_down(s, off, 64);
    if ((threadIdx.x & 63) == 0) sm[threadIdx.x >> 6] = s;
    __syncthreads();
    float inv = 1.0f / sqrtf(sm[0] + sm[1] + sm[2] + sm[3]);
    ushort* o = out + (size_t)row * D;
    for (int i = threadIdx.x; i < D; i += 256) o[i] = f2b(x[i] * inv);
}

// ---------------- row L2-normalize bf16 in-place, D==1024 ----------------
__global__ __launch_bounds__(256) void normalize_bf16_inplace(ushort* __restrict__ buf) {
    int row = blockIdx.x;
    uint2* p2 = (uint2*)(buf + (size_t)row * 1024);
    uint2 u = p2[threadIdx.x];
    float v0 = b2f(u.x & 0xffff), v1 = b2f(u.x >> 16);
    float v2 = b2f(u.y & 0xffff), v3 = b2f(u.y >> 16);
    float s = v0 * v0 + v1 * v1 + v2 * v2 + v3 * v3;
    __shared__ float sm[4];
    #pragma unroll
    for (int off = 32; off; off >>= 1) s += __shfl_down(s, off, 64);
    if ((threadIdx.x & 63) == 0) sm[threadIdx.x >> 6] = s;
    __syncthreads();
    float inv = 1.0f / sqrtf(sm[0] + sm[1] + sm[2] + sm[3]);
    uint2 o;
    o.x = (uint32_t)f2b(v0 * inv) | ((uint32_t)f2b(v1 * inv) << 16);
    o.y = (uint32_t)f2b(v2 * inv) | ((uint32_t)f2b(v3 * inv) << 16);
    p2[threadIdx.x] = o;
}

// ---------------- bf16 MFMA GEMM: C[M,N] = scale*(A[M,K] @ B[N,K]^T) + bias ----------
// 128x128 tile, BK=32, 4 waves each computing 4x4 grid of 16x16x32 MFMA tiles.
// global_load_lds width-16 staging (m97 structure). M%128==0, K%32==0.
// NGUARD: N not multiple of 128 (B rows clamped, stores guarded).
template<typename OutT, bool NGUARD>
__global__ __launch_bounds__(256) void gemm_bt(
    const ushort* __restrict__ A, const ushort* __restrict__ B,
    const float* __restrict__ bias, OutT* __restrict__ C,
    int M, int N, int K, int Nld, float scale)
{
    __shared__ alignas(16) ushort As[128 * 32];
    __shared__ alignas(16) ushort Bs[128 * 32];
    const int id = threadIdx.x;
    const int wave = id >> 6, lane = id & 63;
    const int row0 = blockIdx.y * 128, col0 = blockIdx.x * 128;
    const int wm = (wave >> 1) * 64, wn = (wave & 1) * 64;

    // staging: flat 16B-chunk index f in [0,512); row = f>>2, k-seg = (f&3)*8 elems
    const int f0 = id, f1 = id + 256;
    const int ar0 = f0 >> 2, as0 = (f0 & 3) * 8;
    const int ar1 = f1 >> 2, as1 = (f1 & 3) * 8;
    int brow0 = col0 + ar0, brow1 = col0 + ar1;
    if (NGUARD) { brow0 = min(brow0, N - 1); brow1 = min(brow1, N - 1); }

    const ushort* Ag0 = A + (size_t)(row0 + ar0) * K + as0;
    const ushort* Ag1 = A + (size_t)(row0 + ar1) * K + as1;
    const ushort* Bg0 = B + (size_t)brow0 * K + as0;
    const ushort* Bg1 = B + (size_t)brow1 * K + as1;

    floatx4 acc[4][4] = {};
    const int mrow = lane & 15, koff = (lane >> 4) * 8;

    for (int k0 = 0; k0 < K; k0 += 32) {
        gl_lds16(Ag0 + k0, &As[f0 * 8]);
        gl_lds16(Ag1 + k0, &As[f1 * 8]);
        gl_lds16(Bg0 + k0, &Bs[f0 * 8]);
        gl_lds16(Bg1 + k0, &Bs[f1 * 8]);
        __syncthreads();   // drains vmcnt -> LDS visible
        short8 a[4], b[4];
        #pragma unroll
        for (int i = 0; i < 4; i++)
            a[i] = *(const short8*)&As[(wm + i * 16 + mrow) * 32 + koff];
        #pragma unroll
        for (int j = 0; j < 4; j++)
            b[j] = *(const short8*)&Bs[(wn + j * 16 + mrow) * 32 + koff];
        #pragma unroll
        for (int i = 0; i < 4; i++)
            #pragma unroll
            for (int j = 0; j < 4; j++)
                acc[i][j] = __builtin_amdgcn_mfma_f32_16x16x32_bf16(a[i], b[j], acc[i][j], 0, 0, 0);
        __syncthreads();
    }

    // C/D layout: col = lane&15, row = (lane>>4)*4 + r   [m89/m91-verified]
    const int ccol_base = col0 + wn + (lane & 15);
    const int crow_base = row0 + wm + (lane >> 4) * 4;
    #pragma unroll
    for (int j = 0; j < 4; j++) {
        int col = ccol_base + j * 16;
        if (NGUARD && col >= N) continue;
        float bv = bias ? bias[col] : 0.0f;
        #pragma unroll
        for (int i = 0; i < 4; i++) {
            #pragma unroll
            for (int r = 0; r < 4; r++) {
                int row = crow_base + i * 16 + r;
                float v = acc[i][j][r] * scale + bv;
                if constexpr (sizeof(OutT) == 2) C[(size_t)row * Nld + col] = (OutT)f2b(v);
                else                             C[(size_t)row * Nld + col] = v;
            }
        }
    }
}

// --------- sparsemax rows of 512, in-place f32 + bf16 copy; 1 wave per row ----------
__global__ __launch_bounds__(256) void sparsemax_k(float* __restrict__ S,
                                                   ushort* __restrict__ Ab) {
    int wave = threadIdx.x >> 6, lane = threadIdx.x & 63;
    int row = blockIdx.x * 4 + wave;
    float* z = S + (size_t)row * 512;
    float v[8];
    #pragma unroll
    for (int j = 0; j < 8; j++) v[j] = z[lane + 64 * j];
    float mx = v[0];
    #pragma unroll
    for (int j = 1; j < 8; j++) mx = fmaxf(mx, v[j]);
    #pragma unroll
    for (int off = 1; off < 64; off <<= 1) mx = fmaxf(mx, __shfl_xor(mx, off, 64));
    float lo = mx - 1.0f, hi = mx;
    for (int it = 0; it < 30; it++) {
        float tau = 0.5f * (lo + hi);
        float s = 0.0f;
        #pragma unroll
        for (int j = 0; j < 8; j++) s += fmaxf(v[j] - tau, 0.0f);
        #pragma unroll
        for (int off = 1; off < 64; off <<= 1) s += __shfl_xor(s, off, 64);
        if (s >= 1.0f) lo = tau; else hi = tau;   // bit-identical across lanes
    }
    float tau = 0.5f * (lo + hi);
    ushort* ob = Ab + (size_t)row * 512;
    #pragma unroll
    for (int j = 0; j < 8; j++) {
        float o = fmaxf(v[j] - tau, 0.0f);
        z[lane + 64 * j] = o;
        ob[lane + 64 * j] = f2b(o);
    }
}

extern "C" void kernel_launch(void* const* d_in, const int* in_sizes, int n_in,
                              void* d_out, int out_size, void* d_ws, size_t ws_size,
                              hipStream_t stream) {
    const float* x        = (const float*)d_in[0];   // [16384,1024]
    const float* concepts = (const float*)d_in[1];   // [512,1024]
    const float* Wq       = (const float*)d_in[2];   // [1024,1024]
    const float* Wk       = (const float*)d_in[3];   // [1024,1024]
    const float* fc_w     = (const float*)d_in[4];   // [1000,1024]
    const float* fc_b     = (const float*)d_in[5];   // [1000]

    const int B = 16384, D = 1024, C = 512, N = 1000;

    float* out  = (float*)d_out;                       // [B,N]
    float* attn = out + (size_t)B * N;                 // [B,C] (f32 scores -> sparsemax in place)
    float* sim  = attn + (size_t)B * C;                // [C,C]

    // ---- ws layout (67 MiB; lifetimes disjoint where overlapped) ----
    uint8_t* w = (uint8_t*)d_ws;
    ushort* x_bf    = (ushort*)w;                          // [B,D]   32 MiB, dead after q GEMM
    ushort* WkT     = (ushort*)w;                          // [D,D]    2 MiB (after x dead)
    ushort* attn_bf = (ushort*)w;                          // [B,C]   16 MiB (after WkT dead)
    ushort* fcw_bf  = (ushort*)(w + (16ull << 20));        // [N,D]    2 MiB
    ushort* q_bf    = (ushort*)(w + (32ull << 20));        // [B,D]   32 MiB
    ushort* summary = q_bf;                                //          (q dead by then)
    ushort* WqT     = (ushort*)(w + (64ull << 20));        // [D,D]    2 MiB, dead after q GEMM
    ushort* c_bf    = (ushort*)(w + (64ull << 20));        // [C,D]    1 MiB (after WqT dead)
    ushort* cT      = (ushort*)(w + (65ull << 20));        // [D,C]    1 MiB
    ushort* kmat    = (ushort*)(w + (66ull << 20));        // [C,D]    1 MiB

    // 1. x -> bf16 ; WqT ; q = x @ Wq
    convert_f32_bf16<<<(B * D / 4 + 255) / 256, 256, 0, stream>>>(x, x_bf, B * D / 4);
    transpose_f32_to_bf16<<<dim3(D / 32, D / 32), 256, 0, stream>>>(Wq, WqT, D, D);
    gemm_bt<ushort, false><<<dim3(D / 128, B / 128), 256, 0, stream>>>(
        x_bf, WqT, nullptr, q_bf, B, D, D, D, 1.0f);
    // 2. concepts pipeline (x_bf, WqT now dead)
    normalize_f32_to_bf16<<<C, 256, 0, stream>>>(concepts, c_bf, D);
    transpose_bf16<<<dim3(D / 32, C / 32), 256, 0, stream>>>(c_bf, cT, C, D);
    transpose_f32_to_bf16<<<dim3(D / 32, D / 32), 256, 0, stream>>>(Wk, WkT, D, D);
    gemm_bt<ushort, false><<<dim3(D / 128, C / 128), 256, 0, stream>>>(
        c_bf, WkT, nullptr, kmat, C, D, D, D, 1.0f);
    gemm_bt<float, false><<<dim3(C / 128, C / 128), 256, 0, stream>>>(
        c_bf, c_bf, nullptr, sim, C, C, D, C, 1.0f);
    // 3. scores = (q @ k^T)/32 -> attn slot of d_out
    gemm_bt<float, false><<<dim3(C / 128, B / 128), 256, 0, stream>>>(
        q_bf, kmat, nullptr, attn, B, C, D, C, 0.03125f);
    // 4. sparsemax in place + bf16 copy (WkT dead -> attn_bf region free)
    sparsemax_k<<<B / 4, 256, 0, stream>>>(attn, attn_bf);
    // 5. fc weights -> bf16
    convert_f32_bf16<<<(N * D / 4 + 255) / 256, 256, 0, stream>>>(fc_w, fcw_bf, N * D / 4);
    // 6. summary = attn @ c  (bf16 out into q buffer), row-normalize
    gemm_bt<ushort, false><<<dim3(D / 128, B / 128), 256, 0, stream>>>(
        attn_bf, cT, nullptr, summary, B, D, C, D, 1.0f);
    normalize_bf16_inplace<<<B, 256, 0, stream>>>(summary);
    // 7. out = summary @ fc_w^T + fc_b
    gemm_bt<float, true><<<dim3((N + 127) / 128, B / 128), 256, 0, stream>>>(
        summary, fcw_bf, fc_b, out, B, N, D, N, 1.0f);
}

// Round 3
// 380.377 us; speedup vs baseline: 4.6851x; 1.2308x over previous
//
#include <hip/hip_runtime.h>
#include <hip/hip_bf16.h>
#include <stdint.h>

typedef __attribute__((ext_vector_type(8))) short short8;
typedef __attribute__((ext_vector_type(4))) float floatx4;

__device__ __forceinline__ ushort f2b(float f) {
    union { float f; uint32_t u; } v; v.f = f;
    uint32_t r = (v.u + 0x7fffu + ((v.u >> 16) & 1u)) >> 16;
    return (ushort)r;
}
__device__ __forceinline__ float b2f(ushort b) {
    union { uint32_t u; float f; } v; v.u = ((uint32_t)b) << 16;
    return v.f;
}

__device__ __forceinline__ void gl_lds16(const void* g, void* l) {
    __builtin_amdgcn_global_load_lds(
        (const __attribute__((address_space(1))) void*)g,
        (__attribute__((address_space(3))) void*)l, 16, 0, 0);
}

// ---------------- elementwise f32 -> bf16 (float4 in, ushort4 out) ----------------
__global__ __launch_bounds__(256) void convert_f32_bf16(const float* __restrict__ in,
                                                        ushort* __restrict__ out, int n4) {
    int i = blockIdx.x * 256 + threadIdx.x;
    if (i < n4) {
        float4 v = ((const float4*)in)[i];
        ushort4 o;
        o.x = f2b(v.x); o.y = f2b(v.y); o.z = f2b(v.z); o.w = f2b(v.w);
        ((ushort4*)out)[i] = o;
    }
}

// ---------------- transpose f32[R,C] -> bf16[C,R] ----------------
__global__ __launch_bounds__(256) void transpose_f32_to_bf16(const float* __restrict__ in,
                                                             ushort* __restrict__ out,
                                                             int R, int Cc) {
    __shared__ ushort t[32][33];
    int bx = blockIdx.x * 32;
    int by = blockIdx.y * 32;
    int tx = threadIdx.x & 31, ty = threadIdx.x >> 5;
    #pragma unroll
    for (int i = 0; i < 32; i += 8)
        t[ty + i][tx] = f2b(in[(size_t)(by + ty + i) * Cc + bx + tx]);
    __syncthreads();
    #pragma unroll
    for (int i = 0; i < 32; i += 8)
        out[(size_t)(bx + ty + i) * R + by + tx] = t[tx][ty + i];
}

// ---------------- transpose bf16[R,C] -> bf16[C,R] ----------------
__global__ __launch_bounds__(256) void transpose_bf16(const ushort* __restrict__ in,
                                                      ushort* __restrict__ out,
                                                      int R, int Cc) {
    __shared__ ushort t[32][33];
    int bx = blockIdx.x * 32;
    int by = blockIdx.y * 32;
    int tx = threadIdx.x & 31, ty = threadIdx.x >> 5;
    #pragma unroll
    for (int i = 0; i < 32; i += 8)
        t[ty + i][tx] = in[(size_t)(by + ty + i) * Cc + bx + tx];
    __syncthreads();
    #pragma unroll
    for (int i = 0; i < 32; i += 8)
        out[(size_t)(bx + ty + i) * R + by + tx] = t[tx][ty + i];
}

// ---------------- row L2-normalize f32 in -> bf16 out ----------------
__global__ __launch_bounds__(256) void normalize_f32_to_bf16(const float* __restrict__ in,
                                                             ushort* __restrict__ out, int D) {
    int row = blockIdx.x;
    const float* x = in + (size_t)row * D;
    float s = 0.0f;
    for (int i = threadIdx.x; i < D; i += 256) { float t = x[i]; s += t * t; }
    __shared__ float sm[4];
    #pragma unroll
    for (int off = 32; off; off >>= 1) s += __shfl_down(s, off, 64);
    if ((threadIdx.x & 63) == 0) sm[threadIdx.x >> 6] = s;
    __syncthreads();
    float inv = 1.0f / sqrtf(sm[0] + sm[1] + sm[2] + sm[3]);
    ushort* o = out + (size_t)row * D;
    for (int i = threadIdx.x; i < D; i += 256) o[i] = f2b(x[i] * inv);
}

// ---------------- bf16 MFMA GEMM: C[M,N] = scale*(A @ B^T) [+bias][*rsqrt(rn)] ------
// 128x128 tile, BK=32, m97 structure. XCD swizzle when gridDim.y%8==0.
// SUMSQ: atomically accumulate per-row sum(v^2) into rn.
// ROWSCALE: multiply row by rsqrt(rn[row]) before bias.
template<typename OutT, bool NGUARD, bool SUMSQ, bool ROWSCALE>
__global__ __launch_bounds__(256, 4) void gemm_bt(
    const ushort* __restrict__ A, const ushort* __restrict__ B,
    const float* __restrict__ bias, float* __restrict__ rn, OutT* __restrict__ C,
    int M, int N, int K, int Nld, float scale)
{
    __shared__ alignas(16) ushort As[128 * 32];
    __shared__ alignas(16) ushort Bs[128 * 32];
    const int id = threadIdx.x;
    const int wave = id >> 6, lane = id & 63;

    // XCD-aware swizzle: all col-blocks of one row-panel -> same XCD (i%8 heuristic)
    int bxi = blockIdx.x, byi = blockIdx.y;
    if ((gridDim.y & 7) == 0) {
        int i = byi * gridDim.x + bxi;
        int xcd = i & 7;
        int j = i >> 3;
        bxi = j % gridDim.x;
        byi = xcd + 8 * (j / gridDim.x);
    }
    const int row0 = byi * 128, col0 = bxi * 128;
    const int wm = (wave >> 1) * 64, wn = (wave & 1) * 64;

    const int f0 = id, f1 = id + 256;
    const int ar0 = f0 >> 2, as0 = (f0 & 3) * 8;
    const int ar1 = f1 >> 2, as1 = (f1 & 3) * 8;
    int brow0 = col0 + ar0, brow1 = col0 + ar1;
    if (NGUARD) { brow0 = min(brow0, N - 1); brow1 = min(brow1, N - 1); }

    const ushort* Ag0 = A + (size_t)(row0 + ar0) * K + as0;
    const ushort* Ag1 = A + (size_t)(row0 + ar1) * K + as1;
    const ushort* Bg0 = B + (size_t)brow0 * K + as0;
    const ushort* Bg1 = B + (size_t)brow1 * K + as1;

    floatx4 acc[4][4] = {};
    const int mrow = lane & 15, koff = (lane >> 4) * 8;

    for (int k0 = 0; k0 < K; k0 += 32) {
        gl_lds16(Ag0 + k0, &As[f0 * 8]);
        gl_lds16(Ag1 + k0, &As[f1 * 8]);
        gl_lds16(Bg0 + k0, &Bs[f0 * 8]);
        gl_lds16(Bg1 + k0, &Bs[f1 * 8]);
        __syncthreads();
        short8 a[4], b[4];
        #pragma unroll
        for (int i = 0; i < 4; i++)
            a[i] = *(const short8*)&As[(wm + i * 16 + mrow) * 32 + koff];
        #pragma unroll
        for (int j = 0; j < 4; j++)
            b[j] = *(const short8*)&Bs[(wn + j * 16 + mrow) * 32 + koff];
        #pragma unroll
        for (int i = 0; i < 4; i++)
            #pragma unroll
            for (int j = 0; j < 4; j++)
                acc[i][j] = __builtin_amdgcn_mfma_f32_16x16x32_bf16(a[i], b[j], acc[i][j], 0, 0, 0);
        __syncthreads();
    }

    // C/D layout: col = lane&15, row = (lane>>4)*4 + r
    const int ccol0 = col0 + wn + (lane & 15);
    const int crow0 = row0 + wm + (lane >> 4) * 4;
    float bv[4];
    #pragma unroll
    for (int j = 0; j < 4; j++) {
        int col = ccol0 + j * 16;
        bv[j] = (bias && (!NGUARD || col < N)) ? bias[col] : 0.0f;
    }
    #pragma unroll
    for (int i = 0; i < 4; i++) {
        #pragma unroll
        for (int r = 0; r < 4; r++) {
            const int row = crow0 + i * 16 + r;
            float inv = 1.0f;
            if constexpr (ROWSCALE) inv = rsqrtf(rn[row]);
            float ss = 0.0f;
            #pragma unroll
            for (int j = 0; j < 4; j++) {
                int col = ccol0 + j * 16;
                float v = acc[i][j][r] * scale * inv + bv[j];
                if constexpr (SUMSQ) ss += v * v;
                if (!NGUARD || col < N) {
                    if constexpr (sizeof(OutT) == 2) C[(size_t)row * Nld + col] = (OutT)f2b(v);
                    else                             C[(size_t)row * Nld + col] = v;
                }
            }
            if constexpr (SUMSQ) {
                #pragma unroll
                for (int m = 1; m < 16; m <<= 1) ss += __shfl_xor(ss, m, 64);
                if ((lane & 15) == 0) atomicAdd(&rn[row], ss);
            }
        }
    }
}

// ------------- fused concept GEMMs: kmat = c@WkT^T (bf16) and sim = c@c^T (f32) -----
// grid (12, 4): blockIdx.x<8 -> kmat cols, >=8 -> sim cols. M=512, K=1024.
__global__ __launch_bounds__(256) void gemm_concepts(
    const ushort* __restrict__ cbf, const ushort* __restrict__ WkT,
    ushort* __restrict__ kmat, float* __restrict__ sim)
{
    __shared__ alignas(16) ushort As[128 * 32];
    __shared__ alignas(16) ushort Bs[128 * 32];
    const int K = 1024;
    const int id = threadIdx.x;
    const int wave = id >> 6, lane = id & 63;
    const bool issim = blockIdx.x >= 8;
    const ushort* B = issim ? cbf : WkT;
    const int col0 = (issim ? (int)blockIdx.x - 8 : (int)blockIdx.x) * 128;
    const int row0 = blockIdx.y * 128;
    const int wm = (wave >> 1) * 64, wn = (wave & 1) * 64;

    const int f0 = id, f1 = id + 256;
    const int ar0 = f0 >> 2, as0 = (f0 & 3) * 8;
    const int ar1 = f1 >> 2, as1 = (f1 & 3) * 8;

    const ushort* Ag0 = cbf + (size_t)(row0 + ar0) * K + as0;
    const ushort* Ag1 = cbf + (size_t)(row0 + ar1) * K + as1;
    const ushort* Bg0 = B + (size_t)(col0 + ar0) * K + as0;
    const ushort* Bg1 = B + (size_t)(col0 + ar1) * K + as1;

    floatx4 acc[4][4] = {};
    const int mrow = lane & 15, koff = (lane >> 4) * 8;

    for (int k0 = 0; k0 < K; k0 += 32) {
        gl_lds16(Ag0 + k0, &As[f0 * 8]);
        gl_lds16(Ag1 + k0, &As[f1 * 8]);
        gl_lds16(Bg0 + k0, &Bs[f0 * 8]);
        gl_lds16(Bg1 + k0, &Bs[f1 * 8]);
        __syncthreads();
        short8 a[4], b[4];
        #pragma unroll
        for (int i = 0; i < 4; i++)
            a[i] = *(const short8*)&As[(wm + i * 16 + mrow) * 32 + koff];
        #pragma unroll
        for (int j = 0; j < 4; j++)
            b[j] = *(const short8*)&Bs[(wn + j * 16 + mrow) * 32 + koff];
        #pragma unroll
        for (int i = 0; i < 4; i++)
            #pragma unroll
            for (int j = 0; j < 4; j++)
                acc[i][j] = __builtin_amdgcn_mfma_f32_16x16x32_bf16(a[i], b[j], acc[i][j], 0, 0, 0);
        __syncthreads();
    }

    const int ccol0 = col0 + wn + (lane & 15);
    const int crow0 = row0 + wm + (lane >> 4) * 4;
    #pragma unroll
    for (int i = 0; i < 4; i++)
        #pragma unroll
        for (int r = 0; r < 4; r++) {
            const int row = crow0 + i * 16 + r;
            #pragma unroll
            for (int j = 0; j < 4; j++) {
                int col = ccol0 + j * 16;
                float v = acc[i][j][r];
                if (issim) sim[(size_t)row * 512 + col] = v;
                else       kmat[(size_t)row * 1024 + col] = f2b(v);
            }
        }
}

// --------- sparsemax rows of 512, in-place f32 + bf16 copy; 1 wave per row ----------
__global__ __launch_bounds__(256) void sparsemax_k(float* __restrict__ S,
                                                   ushort* __restrict__ Ab) {
    int wave = threadIdx.x >> 6, lane = threadIdx.x & 63;
    int row = blockIdx.x * 4 + wave;
    float* z = S + (size_t)row * 512;
    float v[8];
    #pragma unroll
    for (int j = 0; j < 8; j++) v[j] = z[lane + 64 * j];
    float mx = v[0];
    #pragma unroll
    for (int j = 1; j < 8; j++) mx = fmaxf(mx, v[j]);
    #pragma unroll
    for (int off = 1; off < 64; off <<= 1) mx = fmaxf(mx, __shfl_xor(mx, off, 64));
    float lo = mx - 1.0f, hi = mx;
    for (int it = 0; it < 30; it++) {
        float tau = 0.5f * (lo + hi);
        float s = 0.0f;
        #pragma unroll
        for (int j = 0; j < 8; j++) s += fmaxf(v[j] - tau, 0.0f);
        #pragma unroll
        for (int off = 1; off < 64; off <<= 1) s += __shfl_xor(s, off, 64);
        if (s >= 1.0f) lo = tau; else hi = tau;
    }
    float tau = 0.5f * (lo + hi);
    ushort* ob = Ab + (size_t)row * 512;
    #pragma unroll
    for (int j = 0; j < 8; j++) {
        float o = fmaxf(v[j] - tau, 0.0f);
        z[lane + 64 * j] = o;
        ob[lane + 64 * j] = f2b(o);
    }
}

extern "C" void kernel_launch(void* const* d_in, const int* in_sizes, int n_in,
                              void* d_out, int out_size, void* d_ws, size_t ws_size,
                              hipStream_t stream) {
    const float* x        = (const float*)d_in[0];   // [16384,1024]
    const float* concepts = (const float*)d_in[1];   // [512,1024]
    const float* Wq       = (const float*)d_in[2];   // [1024,1024]
    const float* Wk       = (const float*)d_in[3];   // [1024,1024]
    const float* fc_w     = (const float*)d_in[4];   // [1000,1024]
    const float* fc_b     = (const float*)d_in[5];   // [1000]

    const int B = 16384, D = 1024, C = 512, N = 1000;

    float* out  = (float*)d_out;                       // [B,N]
    float* attn = out + (size_t)B * N;                 // [B,C]
    float* sim  = attn + (size_t)B * C;                // [C,C]

    // ---- ws layout (67 MiB + 64 KiB; overlapped lifetimes are disjoint in time) ----
    uint8_t* w = (uint8_t*)d_ws;
    ushort* x_bf    = (ushort*)w;                          // [B,D]   32 MiB (dead after q)
    ushort* WkT     = (ushort*)w;                          // [D,D]    2 MiB (after x dead)
    ushort* attn_bf = (ushort*)w;                          // [B,C]   16 MiB (after WkT dead)
    ushort* fcw_bf  = (ushort*)(w + (16ull << 20));        // [N,D]    2 MiB
    ushort* q_bf    = (ushort*)(w + (32ull << 20));        // [B,D]   32 MiB
    ushort* summary = q_bf;                                //          (q dead by then)
    ushort* WqT     = (ushort*)(w + (64ull << 20));        // [D,D]    2 MiB (dead after q)
    ushort* c_bf    = (ushort*)(w + (64ull << 20));        // [C,D]    1 MiB (after WqT dead)
    ushort* cT      = (ushort*)(w + (65ull << 20));        // [D,C]    1 MiB
    ushort* kmat    = (ushort*)(w + (66ull << 20));        // [C,D]    1 MiB
    float*  rn      = (float*)(w + (67ull << 20));         // [B]     64 KiB row sumsq

    // 1. x -> bf16 ; WqT ; q = x @ Wq
    convert_f32_bf16<<<(B * D / 4 + 255) / 256, 256, 0, stream>>>(x, x_bf, B * D / 4);
    transpose_f32_to_bf16<<<dim3(D / 32, D / 32), 256, 0, stream>>>(Wq, WqT, D, D);
    gemm_bt<ushort, false, false, false><<<dim3(D / 128, B / 128), 256, 0, stream>>>(
        x_bf, WqT, nullptr, nullptr, q_bf, B, D, D, D, 1.0f);
    // 2. concepts pipeline (x_bf, WqT now dead)
    normalize_f32_to_bf16<<<C, 256, 0, stream>>>(concepts, c_bf, D);
    transpose_bf16<<<dim3(D / 32, C / 32), 256, 0, stream>>>(c_bf, cT, C, D);
    transpose_f32_to_bf16<<<dim3(D / 32, D / 32), 256, 0, stream>>>(Wk, WkT, D, D);
    gemm_concepts<<<dim3(12, C / 128), 256, 0, stream>>>(c_bf, WkT, kmat, sim);
    // 3. scores = (q @ k^T)/32 -> attn slot of d_out
    gemm_bt<float, false, false, false><<<dim3(C / 128, B / 128), 256, 0, stream>>>(
        q_bf, kmat, nullptr, nullptr, attn, B, C, D, C, 0.03125f);
    // 4. sparsemax in place + bf16 copy (WkT dead -> attn_bf region free)
    sparsemax_k<<<B / 4, 256, 0, stream>>>(attn, attn_bf);
    // 5. fc weights -> bf16
    convert_f32_bf16<<<(N * D / 4 + 255) / 256, 256, 0, stream>>>(fc_w, fcw_bf, N * D / 4);
    // 6. summary = attn @ c (bf16 into q buffer) + per-row sumsq into rn
    hipMemsetAsync(rn, 0, B * sizeof(float), stream);
    gemm_bt<ushort, false, true, false><<<dim3(D / 128, B / 128), 256, 0, stream>>>(
        attn_bf, cT, nullptr, rn, summary, B, D, C, D, 1.0f);
    // 7. out = (summary * rsqrt(rn)) @ fc_w^T + fc_b   (row-norm folded into epilogue)
    gemm_bt<float, true, false, true><<<dim3((N + 127) / 128, B / 128), 256, 0, stream>>>(
        summary, fcw_bf, fc_b, rn, out, B, N, D, N, 1.0f);
}

// Round 4
// 323.313 us; speedup vs baseline: 5.5120x; 1.1765x over previous
//
#include <hip/hip_runtime.h>
#include <hip/hip_bf16.h>
#include <stdint.h>

typedef __attribute__((ext_vector_type(8))) short short8;
typedef __attribute__((ext_vector_type(4))) float floatx4;
typedef __attribute__((ext_vector_type(8))) int int8v;
typedef __attribute__((ext_vector_type(4))) int int4v;

__device__ __forceinline__ ushort f2b(float f) {
    union { float f; uint32_t u; } v; v.f = f;
    uint32_t r = (v.u + 0x7fffu + ((v.u >> 16) & 1u)) >> 16;
    return (ushort)r;
}
__device__ __forceinline__ float b2f(ushort b) {
    union { uint32_t u; float f; } v; v.u = ((uint32_t)b) << 16;
    return v.f;
}
__device__ __forceinline__ uint8_t f2fp8(float f) {
    return (uint8_t)(__builtin_amdgcn_cvt_pk_fp8_f32(f, f, 0, false) & 0xff);
}

__device__ __forceinline__ void gl_lds16(const void* g, void* l) {
    __builtin_amdgcn_global_load_lds(
        (const __attribute__((address_space(1))) void*)g,
        (__attribute__((address_space(3))) void*)l, 16, 0, 0);
}

// ---------------- elementwise f32 -> fp8 e4m3 (*s), float4 in, 4 bytes out ----------
__global__ __launch_bounds__(256) void convert_f32_fp8(const float* __restrict__ in,
                                                       uint8_t* __restrict__ out,
                                                       int n4, float s) {
    int i = blockIdx.x * 256 + threadIdx.x;
    if (i < n4) {
        float4 v = ((const float4*)in)[i];
        int p = __builtin_amdgcn_cvt_pk_fp8_f32(v.x * s, v.y * s, 0, false);
        p = __builtin_amdgcn_cvt_pk_fp8_f32(v.z * s, v.w * s, p, true);
        ((uint32_t*)out)[i] = p;
    }
}

// ---------------- transpose f32[R,C] -> fp8[C,R] (*s) ----------------
__global__ __launch_bounds__(256) void transpose_f32_to_fp8(const float* __restrict__ in,
                                                            uint8_t* __restrict__ out,
                                                            int R, int Cc, float s) {
    __shared__ uint8_t t[32][36];
    int bx = blockIdx.x * 32, by = blockIdx.y * 32;
    int tx = threadIdx.x & 31, ty = threadIdx.x >> 5;
    #pragma unroll
    for (int i = 0; i < 32; i += 8)
        t[ty + i][tx] = f2fp8(in[(size_t)(by + ty + i) * Cc + bx + tx] * s);
    __syncthreads();
    #pragma unroll
    for (int i = 0; i < 32; i += 8)
        out[(size_t)(bx + ty + i) * R + by + tx] = t[tx][ty + i];
}

// ---------------- transpose bf16[R,C] -> fp8[C,R] (*s) ----------------
__global__ __launch_bounds__(256) void transpose_bf16_to_fp8(const ushort* __restrict__ in,
                                                             uint8_t* __restrict__ out,
                                                             int R, int Cc, float s) {
    __shared__ uint8_t t[32][36];
    int bx = blockIdx.x * 32, by = blockIdx.y * 32;
    int tx = threadIdx.x & 31, ty = threadIdx.x >> 5;
    #pragma unroll
    for (int i = 0; i < 32; i += 8)
        t[ty + i][tx] = f2fp8(b2f(in[(size_t)(by + ty + i) * Cc + bx + tx]) * s);
    __syncthreads();
    #pragma unroll
    for (int i = 0; i < 32; i += 8)
        out[(size_t)(bx + ty + i) * R + by + tx] = t[tx][ty + i];
}

// ---------------- transpose f32[R,C] -> bf16[C,R] (for WkT; concepts stay bf16) -----
__global__ __launch_bounds__(256) void transpose_f32_to_bf16(const float* __restrict__ in,
                                                             ushort* __restrict__ out,
                                                             int R, int Cc) {
    __shared__ ushort t[32][33];
    int bx = blockIdx.x * 32, by = blockIdx.y * 32;
    int tx = threadIdx.x & 31, ty = threadIdx.x >> 5;
    #pragma unroll
    for (int i = 0; i < 32; i += 8)
        t[ty + i][tx] = f2b(in[(size_t)(by + ty + i) * Cc + bx + tx]);
    __syncthreads();
    #pragma unroll
    for (int i = 0; i < 32; i += 8)
        out[(size_t)(bx + ty + i) * R + by + tx] = t[tx][ty + i];
}

// ---------------- row L2-normalize f32 in -> bf16 out ----------------
__global__ __launch_bounds__(256) void normalize_f32_to_bf16(const float* __restrict__ in,
                                                             ushort* __restrict__ out, int D) {
    int row = blockIdx.x;
    const float* x = in + (size_t)row * D;
    float s = 0.0f;
    for (int i = threadIdx.x; i < D; i += 256) { float t = x[i]; s += t * t; }
    __shared__ float sm[4];
    #pragma unroll
    for (int off = 32; off; off >>= 1) s += __shfl_down(s, off, 64);
    if ((threadIdx.x & 63) == 0) sm[threadIdx.x >> 6] = s;
    __syncthreads();
    float inv = 1.0f / sqrtf(sm[0] + sm[1] + sm[2] + sm[3]);
    ushort* o = out + (size_t)row * D;
    for (int i = threadIdx.x; i < D; i += 256) o[i] = f2b(x[i] * inv);
}

// =============== MX-fp8 MFMA GEMM: C = scale*(A @ B^T) [+bias][*rsqrt(rn)] ==========
// 128x128 tile, BK=128 (one 16x16x128 scaled MFMA per frag pair per K-step).
// fp8 e4m3 operands, MX scales fixed at 1.0 (0x7f). 16-B-chunk XOR swizzle on the
// K segments breaks the 128-B-row LDS bank aliasing to 2-way (free, m136), while the
// global_load_lds dest stays wave-uniform-base + lane*16 (source side compensates).
template<typename OutT, bool NGUARD, bool SUMSQ, bool ROWSCALE>
__global__ __launch_bounds__(256, 3) void gemm_f8(
    const uint8_t* __restrict__ A, const uint8_t* __restrict__ B,
    const float* __restrict__ bias, float* __restrict__ rn, OutT* __restrict__ C,
    int M, int N, int K, int Nld, float scale)
{
    __shared__ alignas(16) uint8_t As[128 * 128];
    __shared__ alignas(16) uint8_t Bs[128 * 128];
    const int id = threadIdx.x;
    const int wave = id >> 6, lane = id & 63;

    // XCD-aware swizzle: all col-blocks of one row-panel -> same XCD
    int bxi = blockIdx.x, byi = blockIdx.y;
    if ((gridDim.y & 7) == 0) {
        int i = byi * gridDim.x + bxi;
        int xcd = i & 7;
        int j = i >> 3;
        bxi = j % gridDim.x;
        byi = xcd + 8 * (j / gridDim.x);
    }
    const int row0 = byi * 128, col0 = bxi * 128;
    const int wm = (wave >> 1) * 64, wn = (wave & 1) * 64;

    // staging: dest chunk f = id + 256t (t=0..3 per tile); row = f>>3, destseg = f&7.
    // source seg = destseg ^ (row&7)  (row&7 == (id>>3)&7 since 32t == 0 mod 8)
    const int fr = id >> 3;
    const int fss = (id & 7) ^ (fr & 7);
    const uint8_t* Agp[4];
    const uint8_t* Bgp[4];
    #pragma unroll
    for (int t = 0; t < 4; t++) {
        int ar = row0 + fr + 32 * t;
        int br = col0 + fr + 32 * t;
        if (NGUARD) br = min(br, N - 1);
        Agp[t] = A + (size_t)ar * K + fss * 16;
        Bgp[t] = B + (size_t)br * K + fss * 16;
    }

    floatx4 acc[4][4] = {};
    const int mrow = lane & 15;
    const int g2 = (lane >> 4) * 2;   // two 16-elem segs per lane-group

    for (int k0 = 0; k0 < K; k0 += 128) {
        #pragma unroll
        for (int t = 0; t < 4; t++) {
            gl_lds16(Agp[t] + k0, &As[id * 16 + 4096 * t]);
            gl_lds16(Bgp[t] + k0, &Bs[id * 16 + 4096 * t]);
        }
        __syncthreads();
        int8v a[4], b[4];
        #pragma unroll
        for (int i = 0; i < 4; i++) {
            int r = wm + i * 16 + mrow, rs = r & 7;
            int4v lo = *(const int4v*)&As[r * 128 + ((g2    ) ^ rs) * 16];
            int4v hi = *(const int4v*)&As[r * 128 + ((g2 + 1) ^ rs) * 16];
            a[i] = __builtin_shufflevector(lo, hi, 0, 1, 2, 3, 4, 5, 6, 7);
        }
        #pragma unroll
        for (int j = 0; j < 4; j++) {
            int r = wn + j * 16 + mrow, rs = r & 7;
            int4v lo = *(const int4v*)&Bs[r * 128 + ((g2    ) ^ rs) * 16];
            int4v hi = *(const int4v*)&Bs[r * 128 + ((g2 + 1) ^ rs) * 16];
            b[j] = __builtin_shufflevector(lo, hi, 0, 1, 2, 3, 4, 5, 6, 7);
        }
        #pragma unroll
        for (int i = 0; i < 4; i++)
            #pragma unroll
            for (int j = 0; j < 4; j++)
                acc[i][j] = __builtin_amdgcn_mfma_scale_f32_16x16x128_f8f6f4(
                    a[i], b[j], acc[i][j], 0, 0, 0, 0x7f7f7f7f, 0, 0x7f7f7f7f);
        __syncthreads();
    }

    // C/D layout: col = lane&15, row = (lane>>4)*4 + r  (shape-determined, m121-128)
    const int ccol0 = col0 + wn + (lane & 15);
    const int crow0 = row0 + wm + (lane >> 4) * 4;
    float bv[4];
    #pragma unroll
    for (int j = 0; j < 4; j++) {
        int col = ccol0 + j * 16;
        bv[j] = (bias && (!NGUARD || col < N)) ? bias[col] : 0.0f;
    }
    #pragma unroll
    for (int i = 0; i < 4; i++) {
        #pragma unroll
        for (int r = 0; r < 4; r++) {
            const int row = crow0 + i * 16 + r;
            float inv = 1.0f;
            if constexpr (ROWSCALE) inv = rsqrtf(rn[row]);
            float ss = 0.0f;
            #pragma unroll
            for (int j = 0; j < 4; j++) {
                int col = ccol0 + j * 16;
                float v = acc[i][j][r] * scale * inv + bv[j];
                if constexpr (SUMSQ) ss += v * v;
                if (!NGUARD || col < N) {
                    if constexpr (sizeof(OutT) == 1)      C[(size_t)row * Nld + col] = (OutT)f2fp8(v);
                    else if constexpr (sizeof(OutT) == 2) C[(size_t)row * Nld + col] = (OutT)f2b(v);
                    else                                   C[(size_t)row * Nld + col] = v;
                }
            }
            if constexpr (SUMSQ) {
                #pragma unroll
                for (int m = 1; m < 16; m <<= 1) ss += __shfl_xor(ss, m, 64);
                if ((lane & 15) == 0) atomicAdd(&rn[row], ss);
            }
        }
    }
}

// ------------- fused concept GEMMs (bf16): kmat=c@WkT^T (fp8 x16 out), sim=c@c^T ----
__global__ __launch_bounds__(256) void gemm_concepts(
    const ushort* __restrict__ cbf, const ushort* __restrict__ WkT,
    uint8_t* __restrict__ kmat, float* __restrict__ sim)
{
    __shared__ alignas(16) ushort As[128 * 32];
    __shared__ alignas(16) ushort Bs[128 * 32];
    const int K = 1024;
    const int id = threadIdx.x;
    const int wave = id >> 6, lane = id & 63;
    const bool issim = blockIdx.x >= 8;
    const ushort* B = issim ? cbf : WkT;
    const int col0 = (issim ? (int)blockIdx.x - 8 : (int)blockIdx.x) * 128;
    const int row0 = blockIdx.y * 128;
    const int wm = (wave >> 1) * 64, wn = (wave & 1) * 64;

    const int f0 = id, f1 = id + 256;
    const int ar0 = f0 >> 2, as0 = (f0 & 3) * 8;
    const int ar1 = f1 >> 2, as1 = (f1 & 3) * 8;

    const ushort* Ag0 = cbf + (size_t)(row0 + ar0) * K + as0;
    const ushort* Ag1 = cbf + (size_t)(row0 + ar1) * K + as1;
    const ushort* Bg0 = B + (size_t)(col0 + ar0) * K + as0;
    const ushort* Bg1 = B + (size_t)(col0 + ar1) * K + as1;

    floatx4 acc[4][4] = {};
    const int mrow = lane & 15, koff = (lane >> 4) * 8;

    for (int k0 = 0; k0 < K; k0 += 32) {
        gl_lds16(Ag0 + k0, &As[f0 * 8]);
        gl_lds16(Ag1 + k0, &As[f1 * 8]);
        gl_lds16(Bg0 + k0, &Bs[f0 * 8]);
        gl_lds16(Bg1 + k0, &Bs[f1 * 8]);
        __syncthreads();
        short8 a[4], b[4];
        #pragma unroll
        for (int i = 0; i < 4; i++)
            a[i] = *(const short8*)&As[(wm + i * 16 + mrow) * 32 + koff];
        #pragma unroll
        for (int j = 0; j < 4; j++)
            b[j] = *(const short8*)&Bs[(wn + j * 16 + mrow) * 32 + koff];
        #pragma unroll
        for (int i = 0; i < 4; i++)
            #pragma unroll
            for (int j = 0; j < 4; j++)
                acc[i][j] = __builtin_amdgcn_mfma_f32_16x16x32_bf16(a[i], b[j], acc[i][j], 0, 0, 0);
        __syncthreads();
    }

    const int ccol0 = col0 + wn + (lane & 15);
    const int crow0 = row0 + wm + (lane >> 4) * 4;
    #pragma unroll
    for (int i = 0; i < 4; i++)
        #pragma unroll
        for (int r = 0; r < 4; r++) {
            const int row = crow0 + i * 16 + r;
            #pragma unroll
            for (int j = 0; j < 4; j++) {
                int col = ccol0 + j * 16;
                float v = acc[i][j][r];
                if (issim) sim[(size_t)row * 512 + col] = v;
                else       kmat[(size_t)row * 1024 + col] = f2fp8(v * 16.0f);
            }
        }
}

// --------- sparsemax rows of 512, in-place f32 + fp8(x32) copy; 1 wave per row ------
__global__ __launch_bounds__(256) void sparsemax_k(float* __restrict__ S,
                                                   uint8_t* __restrict__ A8) {
    int wave = threadIdx.x >> 6, lane = threadIdx.x & 63;
    int row = blockIdx.x * 4 + wave;
    float* z = S + (size_t)row * 512;
    float v[8];
    #pragma unroll
    for (int j = 0; j < 8; j++) v[j] = z[lane + 64 * j];
    float mx = v[0];
    #pragma unroll
    for (int j = 1; j < 8; j++) mx = fmaxf(mx, v[j]);
    #pragma unroll
    for (int off = 1; off < 64; off <<= 1) mx = fmaxf(mx, __shfl_xor(mx, off, 64));
    float lo = mx - 1.0f, hi = mx;
    for (int it = 0; it < 30; it++) {
        float tau = 0.5f * (lo + hi);
        float s = 0.0f;
        #pragma unroll
        for (int j = 0; j < 8; j++) s += fmaxf(v[j] - tau, 0.0f);
        #pragma unroll
        for (int off = 1; off < 64; off <<= 1) s += __shfl_xor(s, off, 64);
        if (s >= 1.0f) lo = tau; else hi = tau;
    }
    float tau = 0.5f * (lo + hi);
    uint8_t* o8 = A8 + (size_t)row * 512;
    #pragma unroll
    for (int j = 0; j < 8; j++) {
        float o = fmaxf(v[j] - tau, 0.0f);
        z[lane + 64 * j] = o;
        o8[lane + 64 * j] = f2fp8(o * 32.0f);
    }
}

extern "C" void kernel_launch(void* const* d_in, const int* in_sizes, int n_in,
                              void* d_out, int out_size, void* d_ws, size_t ws_size,
                              hipStream_t stream) {
    const float* x        = (const float*)d_in[0];   // [16384,1024]
    const float* concepts = (const float*)d_in[1];   // [512,1024]
    const float* Wq       = (const float*)d_in[2];   // [1024,1024]
    const float* Wk       = (const float*)d_in[3];   // [1024,1024]
    const float* fc_w     = (const float*)d_in[4];   // [1000,1024]
    const float* fc_b     = (const float*)d_in[5];   // [1000]

    const int B = 16384, D = 1024, C = 512, N = 1000;

    float* out  = (float*)d_out;                       // [B,N]
    float* attn = out + (size_t)B * N;                 // [B,C]
    float* sim  = attn + (size_t)B * C;                // [C,C]

    // ---- ws layout (~47 MiB of the >=67 MiB workspace) ----
    uint8_t* w = (uint8_t*)d_ws;
    uint8_t* x_f8    = w;                              // [B,D] 16 MiB (dead after q GEMM)
    uint8_t* q_f8    = w + (16ull << 20);              // [B,D] 16 MiB (dead after scores)
    uint8_t* summary = q_f8;                           //       reuse
    uint8_t* attn_f8 = w + (32ull << 20);              // [B,C]  8 MiB
    uint8_t* WqT_f8  = w + (40ull << 20);              // [D,D]  1 MiB
    ushort*  WkT     = (ushort*)(w + (41ull << 20));   // [D,D]  2 MiB
    ushort*  c_bf    = (ushort*)(w + (43ull << 20));   // [C,D]  1 MiB
    uint8_t* cT_f8   = w + (44ull << 20);              // [D,C] 0.5 MiB
    uint8_t* kmat_f8 = w + (45ull << 20);              // [C,D] 0.5 MiB
    uint8_t* fcw_f8  = w + (46ull << 20);              // [N,D]  1 MiB
    float*   rn      = (float*)(w + (47ull << 20));    // [B]   64 KiB

    // scale bookkeeping (all exact powers of 2, folded into GEMM output scales):
    //   x *1, Wq *16  -> q GEMM scale 1/16, store q *1
    //   q *1, kmat *16 -> scores scale (1/32)/16 = 1/512, store f32
    //   attn *32, c *16 -> summary scale 64/512 = 1/8, store summary *64 (+rn sumsq)
    //   summary *64, fcw *16 -> fc scale 1/16 (the *64 cancels through rsqrt(rn))

    // 1. x -> fp8 ; WqT -> fp8(*16) ; q = x @ Wq (store fp8)
    convert_f32_fp8<<<(B * D / 4 + 255) / 256, 256, 0, stream>>>(x, x_f8, B * D / 4, 1.0f);
    transpose_f32_to_fp8<<<dim3(D / 32, D / 32), 256, 0, stream>>>(Wq, WqT_f8, D, D, 16.0f);
    gemm_f8<uint8_t, false, false, false><<<dim3(D / 128, B / 128), 256, 0, stream>>>(
        x_f8, WqT_f8, nullptr, nullptr, q_f8, B, D, D, D, 1.0f / 16.0f);
    // 2. concepts pipeline (bf16 MFMA for kmat + sim; fp8 copies for later GEMMs)
    normalize_f32_to_bf16<<<C, 256, 0, stream>>>(concepts, c_bf, D);
    transpose_f32_to_bf16<<<dim3(D / 32, D / 32), 256, 0, stream>>>(Wk, WkT, D, D);
    transpose_bf16_to_fp8<<<dim3(D / 32, C / 32), 256, 0, stream>>>(c_bf, cT_f8, C, D, 16.0f);
    gemm_concepts<<<dim3(12, C / 128), 256, 0, stream>>>(c_bf, WkT, kmat_f8, sim);
    // 3. scores = (q @ k^T)/32 -> attn slot of d_out (f32)
    gemm_f8<float, false, false, false><<<dim3(C / 128, B / 128), 256, 0, stream>>>(
        q_f8, kmat_f8, nullptr, nullptr, attn, B, C, D, C, 1.0f / 512.0f);
    // 4. sparsemax in place + fp8(*32) copy
    sparsemax_k<<<B / 4, 256, 0, stream>>>(attn, attn_f8);
    // 5. fc weights -> fp8(*16)
    convert_f32_fp8<<<(N * D / 4 + 255) / 256, 256, 0, stream>>>(fc_w, fcw_f8, N * D / 4, 16.0f);
    // 6. summary = attn @ c (fp8 *64 into q buffer) + per-row sumsq into rn
    hipMemsetAsync(rn, 0, B * sizeof(float), stream);
    gemm_f8<uint8_t, false, true, false><<<dim3(D / 128, B / 128), 256, 0, stream>>>(
        attn_f8, cT_f8, nullptr, rn, summary, B, D, C, D, 1.0f / 8.0f);
    // 7. out = (summary * rsqrt(rn)) @ fc_w^T + fc_b
    gemm_f8<float, true, false, true><<<dim3((N + 127) / 128, B / 128), 256, 0, stream>>>(
        summary, fcw_f8, fc_b, rn, out, B, N, D, N, 1.0f / 16.0f);
}